// Round 1
// baseline (8239.825 us; speedup 1.0000x reference)
//
#include <hip/hip_runtime.h>
#include <math.h>

// Problem dims
#define TT 256
#define BB 64
#define DD 512
#define HH 512
#define NC 2048  // 4 gates * H, interleaved col = j*4 + g  (g: 0=i,1=f,2=o,3=ctilde)

// Workspace layout (float offsets). Total 53,577,728 floats = 214.3 MB.
#define XT_OFF 0ull          // [16384][512]  xt precompute, row = t*64+b
#define DH_OFF 8388608ull    // [16384][512]  delta_h precompute
#define GP_OFF 16777216ull   // [16384][2048] G_pre = XT@Wx + M@Wm + b  (gate-interleaved cols)
#define WX_OFF 50331648ull   // [512][2048]
#define WH_OFF 51380224ull   // [512][2048]
#define WM_OFF 52428800ull   // [512][2048]
#define BC_OFF 53477376ull   // [2048]
#define H_OFF  53479424ull   // 2 x [64][512] h double buffer
#define C_OFF  53544960ull   // [64][512] c state

__device__ __forceinline__ float sigmoidf_(float v) { return 1.0f / (1.0f + expf(-v)); }

// ---------------------------------------------------------------------------
// Repack gate weights [1536][512] x4 into x/h/m parts with gate-interleaved
// columns: W?[k][j*4+g]. Bias -> BC[j*4+g].
// ---------------------------------------------------------------------------
__global__ __launch_bounds__(256) void repack_kernel(
    const float* __restrict__ Wi, const float* __restrict__ bi,
    const float* __restrict__ Wf, const float* __restrict__ bff,
    const float* __restrict__ Wo, const float* __restrict__ bo,
    const float* __restrict__ Wc, const float* __restrict__ bc,
    float* __restrict__ WX, float* __restrict__ WHc, float* __restrict__ WM,
    float* __restrict__ BC) {
  int idx = blockIdx.x * 256 + threadIdx.x;  // 512*512
  int k = idx >> 9, j = idx & 511;
  const float* Ws[4] = {Wi, Wf, Wo, Wc};
  const float* bs[4] = {bi, bff, bo, bc};
#pragma unroll
  for (int g = 0; g < 4; ++g) {
    const float* W = Ws[g];
    WX[(size_t)k * NC + j * 4 + g] = W[(size_t)k * 512 + j];
    WHc[(size_t)k * NC + j * 4 + g] = W[(size_t)(512 + k) * 512 + j];
    WM[(size_t)k * NC + j * 4 + g] = W[(size_t)(1024 + k) * 512 + j];
    if (k == 0) BC[j * 4 + g] = bs[g][j];
  }
}

// ---------------------------------------------------------------------------
// XT[t*64+b][d] = m*X + (1-m)*(dx*Xl + (1-dx)*xm),  dx = exp(-relu(dl*gxw+gxb))
// x layout: [B][4][T][D]; channel 0=X,1=Xl,2=M,3=Dl
// ---------------------------------------------------------------------------
__global__ __launch_bounds__(256) void xt_kernel(
    const float* __restrict__ x, const float* __restrict__ Xmean,
    const float* __restrict__ gxw, const float* __restrict__ gxb,
    float* __restrict__ XT) {
  int idx = blockIdx.x * 256 + threadIdx.x;  // 2,097,152 float4 slots
  int d = (idx & 127) * 4;
  int r = idx >> 7;  // t*64+b
  int b = r & 63, t = r >> 6;
  size_t base = (((size_t)b * 4) * TT + t) * DD + d;
  const float4 X = *(const float4*)&x[base];
  const float4 Xl = *(const float4*)&x[base + (size_t)TT * DD];
  const float4 M = *(const float4*)&x[base + 2ull * TT * DD];
  const float4 Dl = *(const float4*)&x[base + 3ull * TT * DD];
  const float4 xm = *(const float4*)&Xmean[(size_t)t * DD + d];
  const float4 gw = *(const float4*)&gxw[d];
  const float4 gb = *(const float4*)&gxb[d];
  float4 o;
  {
    float dx = expf(-fmaxf(0.f, Dl.x * gw.x + gb.x));
    o.x = M.x * X.x + (1.f - M.x) * (dx * Xl.x + (1.f - dx) * xm.x);
  }
  {
    float dx = expf(-fmaxf(0.f, Dl.y * gw.y + gb.y));
    o.y = M.y * X.y + (1.f - M.y) * (dx * Xl.y + (1.f - dx) * xm.y);
  }
  {
    float dx = expf(-fmaxf(0.f, Dl.z * gw.z + gb.z));
    o.z = M.z * X.z + (1.f - M.z) * (dx * Xl.z + (1.f - dx) * xm.z);
  }
  {
    float dx = expf(-fmaxf(0.f, Dl.w * gw.w + gb.w));
    o.w = M.w * X.w + (1.f - M.w) * (dx * Xl.w + (1.f - dx) * xm.w);
  }
  *(float4*)&XT[(size_t)r * DD + d] = o;
}

// ---------------------------------------------------------------------------
// DH = exp(-relu(Dl @ gh_W + gh_b)) : [16384,512] @ [512,512]
// fp32 tiled GEMM, BM=BN=64, BK=32, 256 threads, 4x4 microtile.
// ---------------------------------------------------------------------------
__global__ __launch_bounds__(256) void gemm_dh(
    const float* __restrict__ x, const float* __restrict__ ghW,
    const float* __restrict__ ghb, float* __restrict__ DH) {
  __shared__ float As[32][68];
  __shared__ float Bs[32][64];
  const int tid = threadIdx.x;
  const int bx = blockIdx.x, by = blockIdx.y;
  const int tx = tid & 15, ty = tid >> 4;
  float acc[4][4] = {};

  const int arow = tid >> 2, akq = (tid & 3) * 8;
  const int rg = by * 64 + arow;
  const int ab = rg & 63, at = rg >> 6;
  const float* Arow = &x[(((size_t)ab * 4 + 3) * TT + at) * DD];
  const int bk = tid >> 3, bcq = (tid & 7) * 8;

  for (int k0 = 0; k0 < 512; k0 += 32) {
    float4 a0 = *(const float4*)&Arow[k0 + akq];
    float4 a1 = *(const float4*)&Arow[k0 + akq + 4];
    float4 b0 = *(const float4*)&ghW[(size_t)(k0 + bk) * 512 + bx * 64 + bcq];
    float4 b1 = *(const float4*)&ghW[(size_t)(k0 + bk) * 512 + bx * 64 + bcq + 4];
    __syncthreads();
    As[akq + 0][arow] = a0.x; As[akq + 1][arow] = a0.y;
    As[akq + 2][arow] = a0.z; As[akq + 3][arow] = a0.w;
    As[akq + 4][arow] = a1.x; As[akq + 5][arow] = a1.y;
    As[akq + 6][arow] = a1.z; As[akq + 7][arow] = a1.w;
    *(float4*)&Bs[bk][bcq] = b0;
    *(float4*)&Bs[bk][bcq + 4] = b1;
    __syncthreads();
#pragma unroll
    for (int kk = 0; kk < 32; ++kk) {
      float4 av = *(const float4*)&As[kk][ty * 4];
      float4 bv = *(const float4*)&Bs[kk][tx * 4];
      acc[0][0] += av.x * bv.x; acc[0][1] += av.x * bv.y; acc[0][2] += av.x * bv.z; acc[0][3] += av.x * bv.w;
      acc[1][0] += av.y * bv.x; acc[1][1] += av.y * bv.y; acc[1][2] += av.y * bv.z; acc[1][3] += av.y * bv.w;
      acc[2][0] += av.z * bv.x; acc[2][1] += av.z * bv.y; acc[2][2] += av.z * bv.z; acc[2][3] += av.z * bv.w;
      acc[3][0] += av.w * bv.x; acc[3][1] += av.w * bv.y; acc[3][2] += av.w * bv.z; acc[3][3] += av.w * bv.w;
    }
  }
  const int col0 = bx * 64 + tx * 4;
  const int row0 = by * 64 + ty * 4;
#pragma unroll
  for (int i = 0; i < 4; ++i) {
    float4 v;
    v.x = expf(-fmaxf(0.f, acc[i][0] + ghb[col0 + 0]));
    v.y = expf(-fmaxf(0.f, acc[i][1] + ghb[col0 + 1]));
    v.z = expf(-fmaxf(0.f, acc[i][2] + ghb[col0 + 2]));
    v.w = expf(-fmaxf(0.f, acc[i][3] + ghb[col0 + 3]));
    *(float4*)&DH[(size_t)(row0 + i) * 512 + col0] = v;
  }
}

// ---------------------------------------------------------------------------
// G_pre = XT @ WX + M @ WM + BC : [16384,2048], two K=512 passes.
// ---------------------------------------------------------------------------
__global__ __launch_bounds__(256) void gemm_gp(
    const float* __restrict__ x, const float* __restrict__ XT,
    const float* __restrict__ WX, const float* __restrict__ WM,
    const float* __restrict__ BC, float* __restrict__ GP) {
  __shared__ float As[32][68];
  __shared__ float Bs[32][64];
  const int tid = threadIdx.x;
  const int bx = blockIdx.x, by = blockIdx.y;
  const int tx = tid & 15, ty = tid >> 4;
  float acc[4][4] = {};

  const int arow = tid >> 2, akq = (tid & 3) * 8;
  const int rg = by * 64 + arow;
  const int ab = rg & 63, at = rg >> 6;
  const int bk = tid >> 3, bcq = (tid & 7) * 8;

  for (int s = 0; s < 2; ++s) {
    const float* B = s ? WM : WX;
    const float* Arow = s ? &x[(((size_t)ab * 4 + 2) * TT + at) * DD]
                          : &XT[(size_t)rg * DD];
    for (int k0 = 0; k0 < 512; k0 += 32) {
      float4 a0 = *(const float4*)&Arow[k0 + akq];
      float4 a1 = *(const float4*)&Arow[k0 + akq + 4];
      float4 b0 = *(const float4*)&B[(size_t)(k0 + bk) * NC + bx * 64 + bcq];
      float4 b1 = *(const float4*)&B[(size_t)(k0 + bk) * NC + bx * 64 + bcq + 4];
      __syncthreads();
      As[akq + 0][arow] = a0.x; As[akq + 1][arow] = a0.y;
      As[akq + 2][arow] = a0.z; As[akq + 3][arow] = a0.w;
      As[akq + 4][arow] = a1.x; As[akq + 5][arow] = a1.y;
      As[akq + 6][arow] = a1.z; As[akq + 7][arow] = a1.w;
      *(float4*)&Bs[bk][bcq] = b0;
      *(float4*)&Bs[bk][bcq + 4] = b1;
      __syncthreads();
#pragma unroll
      for (int kk = 0; kk < 32; ++kk) {
        float4 av = *(const float4*)&As[kk][ty * 4];
        float4 bv = *(const float4*)&Bs[kk][tx * 4];
        acc[0][0] += av.x * bv.x; acc[0][1] += av.x * bv.y; acc[0][2] += av.x * bv.z; acc[0][3] += av.x * bv.w;
        acc[1][0] += av.y * bv.x; acc[1][1] += av.y * bv.y; acc[1][2] += av.y * bv.z; acc[1][3] += av.y * bv.w;
        acc[2][0] += av.z * bv.x; acc[2][1] += av.z * bv.y; acc[2][2] += av.z * bv.z; acc[2][3] += av.z * bv.w;
        acc[3][0] += av.w * bv.x; acc[3][1] += av.w * bv.y; acc[3][2] += av.w * bv.z; acc[3][3] += av.w * bv.w;
      }
    }
  }
  const int col0 = bx * 64 + tx * 4;
  const int row0 = by * 64 + ty * 4;
  const float4 bc4 = *(const float4*)&BC[col0];
#pragma unroll
  for (int i = 0; i < 4; ++i) {
    float4 v;
    v.x = acc[i][0] + bc4.x;
    v.y = acc[i][1] + bc4.y;
    v.z = acc[i][2] + bc4.z;
    v.w = acc[i][3] + bc4.w;
    *(float4*)&GP[(size_t)(row0 + i) * NC + col0] = v;
  }
}

// ---------------------------------------------------------------------------
// One recurrent step: gates = GP[t] + (DH[t]*h_in) @ WH; update c, h.
// 128 blocks x 256 threads. Block n owns gate cols [n*16, n*16+16) = 4 hidden
// units. Thread = (b = tid>>2, jl = tid&3): computes the 4 gates of (b, j).
// ---------------------------------------------------------------------------
__global__ __launch_bounds__(256) void step_kernel(
    int t, const float* __restrict__ GP, const float* __restrict__ DH,
    const float* __restrict__ WH, const float* __restrict__ h_in,
    float* __restrict__ h_out, float* __restrict__ c_buf,
    float* __restrict__ out) {
  __shared__ float hs[64][68];
  const int n = blockIdx.x;
  const int tid = threadIdx.x;
  const int b = tid >> 2, jl = tid & 3;
  const int colbase = n * 16 + jl * 4;
  float acc0 = 0.f, acc1 = 0.f, acc2 = 0.f, acc3 = 0.f;

  const int bp = tid >> 2, kp0 = (tid & 3) * 16;
  for (int kt = 0; kt < 8; ++kt) {
    __syncthreads();
#pragma unroll
    for (int q = 0; q < 4; ++q) {
      int k = kt * 64 + kp0 + q * 4;
      float4 hv = *(const float4*)&h_in[(size_t)bp * 512 + k];
      float4 dv = *(const float4*)&DH[((size_t)t * 64 + bp) * 512 + k];
      float4 p;
      p.x = hv.x * dv.x; p.y = hv.y * dv.y; p.z = hv.z * dv.z; p.w = hv.w * dv.w;
      *(float4*)&hs[bp][kp0 + q * 4] = p;
    }
    __syncthreads();
#pragma unroll 8
    for (int kk = 0; kk < 64; ++kk) {
      float a = hs[b][kk];
      float4 w = *(const float4*)&WH[(size_t)(kt * 64 + kk) * NC + colbase];
      acc0 += a * w.x; acc1 += a * w.y; acc2 += a * w.z; acc3 += a * w.w;
    }
  }

  const int row = t * 64 + b;
  const float4 gp = *(const float4*)&GP[(size_t)row * NC + colbase];
  float ig = sigmoidf_(acc0 + gp.x);
  float fg = sigmoidf_(acc1 + gp.y);
  float og = sigmoidf_(acc2 + gp.z);
  float ct = tanhf(acc3 + gp.w);
  const int j = n * 4 + jl;
  float c = fg * c_buf[(size_t)b * 512 + j] + ig * ct;
  c_buf[(size_t)b * 512 + j] = c;
  float h = og * tanhf(c);
  h_out[(size_t)b * 512 + j] = h;
  out[((size_t)b * TT + t) * HH + j] = h;
}

// ---------------------------------------------------------------------------
extern "C" void kernel_launch(void* const* d_in, const int* in_sizes, int n_in,
                              void* d_out, int out_size, void* d_ws,
                              size_t ws_size, hipStream_t stream) {
  const float* x = (const float*)d_in[0];
  const float* Xmean = (const float*)d_in[1];
  const float* Wi = (const float*)d_in[2];
  const float* bi = (const float*)d_in[3];
  const float* Wf = (const float*)d_in[4];
  const float* bf = (const float*)d_in[5];
  const float* Wo = (const float*)d_in[6];
  const float* bo = (const float*)d_in[7];
  const float* Wc = (const float*)d_in[8];
  const float* bc = (const float*)d_in[9];
  const float* gxw = (const float*)d_in[10];
  const float* gxb = (const float*)d_in[11];
  const float* ghW = (const float*)d_in[12];
  const float* ghb = (const float*)d_in[13];
  float* out = (float*)d_out;
  float* ws = (float*)d_ws;

  float* XT = ws + XT_OFF;
  float* DH = ws + DH_OFF;
  float* GP = ws + GP_OFF;
  float* WX = ws + WX_OFF;
  float* WH = ws + WH_OFF;
  float* WM = ws + WM_OFF;
  float* BC = ws + BC_OFF;
  float* HB = ws + H_OFF;   // 2 x 32768
  float* CB = ws + C_OFF;   // 32768

  // zero h double-buffer + c state (ws is poisoned 0xAA before every launch)
  hipMemsetAsync(HB, 0, (65536 + 32768) * sizeof(float), stream);

  repack_kernel<<<1024, 256, 0, stream>>>(Wi, bi, Wf, bf, Wo, bo, Wc, bc,
                                          WX, WH, WM, BC);
  xt_kernel<<<8192, 256, 0, stream>>>(x, Xmean, gxw, gxb, XT);
  gemm_dh<<<dim3(8, 256), 256, 0, stream>>>(x, ghW, ghb, DH);
  gemm_gp<<<dim3(32, 256), 256, 0, stream>>>(x, XT, WX, WM, BC, GP);

  for (int t = 0; t < TT; ++t) {
    float* h_in = HB + (size_t)(t & 1) * 32768;
    float* h_out = HB + (size_t)((t & 1) ^ 1) * 32768;
    step_kernel<<<128, 256, 0, stream>>>(t, GP, DH, WH, h_in, h_out, CB, out);
  }
}